// Round 5
// baseline (520.855 us; speedup 1.0000x reference)
//
#include <hip/hip_runtime.h>
#include <hip/hip_bf16.h>
#include <hip/hip_fp16.h>

// Hyperbolic GNN layer. D = 64.
// Edge kernel: 8 edges/wave (8 lanes x 8 f16 per row), f16 tables + f16 pk atomics.

__device__ __forceinline__ float wave_sum(float v) {
#pragma unroll
    for (int off = 32; off > 0; off >>= 1) v += __shfl_xor(v, off, 64);
    return v;
}

// ---- fast HW math ----
__device__ __forceinline__ float frcp(float x) {
#if __has_builtin(__builtin_amdgcn_rcpf)
    return __builtin_amdgcn_rcpf(x);
#else
    return 1.f / x;
#endif
}
__device__ __forceinline__ float fsqrt_(float x) {
#if __has_builtin(__builtin_amdgcn_sqrtf)
    return __builtin_amdgcn_sqrtf(x);
#else
    return sqrtf(x);
#endif
}
__device__ __forceinline__ float flog2_(float x) {
#if __has_builtin(__builtin_amdgcn_logf)
    return __builtin_amdgcn_logf(x);
#else
    return log2f(x);
#endif
}
__device__ __forceinline__ float fexp2_(float x) {
#if __has_builtin(__builtin_amdgcn_exp2f)
    return __builtin_amdgcn_exp2f(x);
#else
    return exp2f(x);
#endif
}

__device__ __forceinline__ unsigned pk2(float a, float b) {
    __half2 h = __floats2half2_rn(a, b);
    return __builtin_bit_cast(unsigned, h);
}
__device__ __forceinline__ float2 upk2(unsigned u) {
    __half2 h = __builtin_bit_cast(__half2, u);
    return __half22float2(h);
}

// expmap0 scale: s such that expmap0(u) = s*u; x2 = ||s*u||^2
__device__ __forceinline__ void expmap0_scale(float norm, float& s, float& x2) {
    const float maxn = 1.0f - 0.004f;
    float un = fmaxf(norm, 1e-15f);
    float th = tanhf(fminf(un, 15.0f));
    float gs = th / un;
    float ng = gs * norm;
    float ps = ng > maxn ? maxn / ng : 1.0f;
    s = gs * ps;
    float sn = s * norm;
    x2 = sn * sn;
}

// ================= f16 fast path (A == 5) =================

// rel tables (R waves) and query rows (B waves), f16 outputs
__global__ void prep_small16(const int* __restrict__ q_rel,
                             const float* __restrict__ query_embed,
                             const float* __restrict__ Wqr_w,
                             const float* __restrict__ Wqr_b,
                             const float* __restrict__ rela_embed,
                             const float* __restrict__ Wr,
                             __half* __restrict__ hr_h16,   // [R][64]
                             uint4* __restrict__ hr_aux16,  // [R]: {w0..w4,0,y2,0}
                             uint4* __restrict__ preq16,    // [B]: {p0..p4,0,0,0}
                             int R, int B) {
    int w = (blockIdx.x * blockDim.x + threadIdx.x) >> 6;
    int lane = threadIdx.x & 63;
    if (w < R) {
        int r = w;
        float u = rela_embed[r * 64 + lane];
        float p0 = u * u;
        float p1 = u * Wr[0 * 64 + lane];
        float p2 = u * Wr[1 * 64 + lane];
        float p3 = u * Wr[2 * 64 + lane];
        float p4 = u * Wr[3 * 64 + lane];
        float p5 = u * Wr[4 * 64 + lane];
#pragma unroll
        for (int off = 1; off < 64; off <<= 1) {
            p0 += __shfl_xor(p0, off, 64);
            p1 += __shfl_xor(p1, off, 64);
            p2 += __shfl_xor(p2, off, 64);
            p3 += __shfl_xor(p3, off, 64);
            p4 += __shfl_xor(p4, off, 64);
            p5 += __shfl_xor(p5, off, 64);
        }
        float s, y2;
        expmap0_scale(fsqrt_(p0), s, y2);
        hr_h16[r * 64 + lane] = __float2half(s * u);
        if (lane == 0) {
            uint4 o; o.x = pk2(p1, p2); o.y = pk2(p3, p4); o.z = pk2(p5, 0.f); o.w = pk2(y2, 0.f);
            hr_aux16[r] = o;
        }
    } else if (w < R + B) {
        int b = w - R;
        int qr = q_rel[b];
        float q = query_embed[qr * 64 + lane];
        float p1 = q * Wqr_w[0 * 64 + lane];
        float p2 = q * Wqr_w[1 * 64 + lane];
        float p3 = q * Wqr_w[2 * 64 + lane];
        float p4 = q * Wqr_w[3 * 64 + lane];
        float p5 = q * Wqr_w[4 * 64 + lane];
#pragma unroll
        for (int off = 1; off < 64; off <<= 1) {
            p1 += __shfl_xor(p1, off, 64);
            p2 += __shfl_xor(p2, off, 64);
            p3 += __shfl_xor(p3, off, 64);
            p4 += __shfl_xor(p4, off, 64);
            p5 += __shfl_xor(p5, off, 64);
        }
        if (lane == 0) {
            uint4 o;
            o.x = pk2(p1 + Wqr_b[0], p2 + Wqr_b[1]);
            o.y = pk2(p3 + Wqr_b[2], p4 + Wqr_b[3]);
            o.z = pk2(p5 + Wqr_b[4], 0.f);
            o.w = pk2(0.f, 0.f);
            preq16[b] = o;
        }
    }
}

// per-node: hidden16 row + aux {w0..w4,0,x2,s}; quarter-wave, 4 nodes/wave
__global__ void prep_node16(const float* __restrict__ hidden,
                            const float* __restrict__ Ws,
                            __half* __restrict__ hidden16,
                            uint4* __restrict__ hs_aux16,
                            int N) {
    int wid = (blockIdx.x * blockDim.x + threadIdx.x) >> 6;
    int lane = threadIdx.x & 63;
    int q = lane >> 4, j = lane & 15;
    int n = wid * 4 + q;
    bool act = n < N;
    int nc = act ? n : N - 1;

    float4 u = *(const float4*)(hidden + (size_t)nc * 64 + 4 * j);
    float4 w0 = *(const float4*)(Ws + 0 * 64 + 4 * j);
    float4 w1 = *(const float4*)(Ws + 1 * 64 + 4 * j);
    float4 w2 = *(const float4*)(Ws + 2 * 64 + 4 * j);
    float4 w3 = *(const float4*)(Ws + 3 * 64 + 4 * j);
    float4 w4 = *(const float4*)(Ws + 4 * 64 + 4 * j);

#define DOT4(a, b) (fmaf((a).x, (b).x, fmaf((a).y, (b).y, fmaf((a).z, (b).z, (a).w * (b).w))))
    float p0 = DOT4(u, u);
    float p1 = DOT4(u, w0);
    float p2 = DOT4(u, w1);
    float p3 = DOT4(u, w2);
    float p4 = DOT4(u, w3);
    float p5 = DOT4(u, w4);
#undef DOT4
#pragma unroll
    for (int off = 1; off < 16; off <<= 1) {
        p0 += __shfl_xor(p0, off, 64);
        p1 += __shfl_xor(p1, off, 64);
        p2 += __shfl_xor(p2, off, 64);
        p3 += __shfl_xor(p3, off, 64);
        p4 += __shfl_xor(p4, off, 64);
        p5 += __shfl_xor(p5, off, 64);
    }
    float s, x2;
    expmap0_scale(fsqrt_(p0), s, x2);
    if (act) {
        uint2 hp; hp.x = pk2(u.x, u.y); hp.y = pk2(u.z, u.w);
        *(uint2*)(hidden16 + (size_t)n * 64 + 4 * j) = hp;
        if (j == 0) {
            uint4 o; o.x = pk2(p1, p2); o.y = pk2(p3, p4); o.z = pk2(p5, 0.f); o.w = pk2(x2, s);
            hs_aux16[n] = o;
        }
    }
}

// main edge kernel: 8 edges per wave (8 lanes x 8 f16), f16 pk atomics
__global__ __launch_bounds__(256) void edge_kernel8(
    const int* __restrict__ edges,
    const __half* __restrict__ hidden16,
    const __half* __restrict__ hr_h16,
    const uint4* __restrict__ hs_aux16,
    const uint4* __restrict__ hr_aux16,
    const uint4* __restrict__ preq16,
    const float* __restrict__ walpha_w,
    const float* __restrict__ walpha_b,
    __half2* __restrict__ agg,
    int E)
{
    int wid = (blockIdx.x * blockDim.x + threadIdx.x) >> 6;
    int lane = threadIdx.x & 63;
    int g = lane >> 3;    // which of 8 edges
    int j = lane & 7;     // 8-f16 chunk within row

    int e = wid * 8 + g;
    bool act = e < E;
    int ec = act ? e : E - 1;

    const long long* er = (const long long*)(edges + (size_t)ec * 6);
    long long ea  = __builtin_nontemporal_load(er);      // r_idx | dummy
    long long eb  = __builtin_nontemporal_load(er + 1);  // rel | dummy
    long long ecd = __builtin_nontemporal_load(er + 2);  // sub | obj
    int r_idx = (int)(ea & 0xffffffffLL);
    int rel   = (int)(eb & 0xffffffffLL);
    int sub   = (int)(ecd & 0xffffffffLL);
    int obj   = (int)(ecd >> 32);

    uint4 hsa = hs_aux16[sub];
    uint4 hra = hr_aux16[rel];
    uint4 pqa = preq16[r_idx];

    float2 hs01 = upk2(hsa.x), hs23 = upk2(hsa.y), hs4 = upk2(hsa.z), hsxs = upk2(hsa.w);
    float2 hr01 = upk2(hra.x), hr23 = upk2(hra.y), hr4 = upk2(hra.z), hry = upk2(hra.w);
    float2 pq01 = upk2(pqa.x), pq23 = upk2(pqa.y), pq4 = upk2(pqa.z);
    float x2 = hsxs.x, s = hsxs.y, y2 = hry.x;

    uint4 hu = *(const uint4*)(hidden16 + (size_t)sub * 64 + 8 * j);
    uint4 yu = *(const uint4*)(hr_h16 + (size_t)rel * 64 + 8 * j);
    float2 h0 = upk2(hu.x), h1 = upk2(hu.y), h2 = upk2(hu.z), h3 = upk2(hu.w);
    float2 v0 = upk2(yu.x), v1 = upk2(yu.y), v2 = upk2(yu.z), v3 = upk2(yu.w);

    float p = h0.x * v0.x;
    p = fmaf(h0.y, v0.y, p);
    p = fmaf(h1.x, v1.x, p);
    p = fmaf(h1.y, v1.y, p);
    p = fmaf(h2.x, v2.x, p);
    p = fmaf(h2.y, v2.y, p);
    p = fmaf(h3.x, v3.x, p);
    p = fmaf(h3.y, v3.y, p);
    p += __shfl_xor(p, 1, 64);
    p += __shfl_xor(p, 2, 64);
    p += __shfl_xor(p, 4, 64);
    float xy = p * s;

    float wa0 = walpha_w[0], wa1 = walpha_w[1], wa2 = walpha_w[2],
          wa3 = walpha_w[3], wa4 = walpha_w[4];
    float z = walpha_b[0];
    z = fmaf(fmaxf(hs01.x + hr01.x + pq01.x, 0.f), wa0, z);
    z = fmaf(fmaxf(hs01.y + hr01.y + pq01.y, 0.f), wa1, z);
    z = fmaf(fmaxf(hs23.x + hr23.x + pq23.x, 0.f), wa2, z);
    z = fmaf(fmaxf(hs23.y + hr23.y + pq23.y, 0.f), wa3, z);
    z = fmaf(fmaxf(hs4.x + hr4.x + pq4.x, 0.f), wa4, z);
    float alpha = frcp(1.f + fexp2_(z * -1.44269504f));

    float Af  = 1.f + 2.f * xy + y2;
    float Bf  = 1.f - x2;
    float den = fmaxf(1.f + 2.f * xy + x2 * y2, 1e-15f);
    float inv = frcp(den);
    float nm2 = fmaxf(fmaf(Af * Af, x2, fmaf(2.f * Af * Bf, xy, Bf * Bf * y2)), 0.f);
    float nm  = fsqrt_(nm2) * inv;
    const float maxn = 1.0f - 0.004f;
    float ps  = nm > maxn ? maxn * frcp(nm) : 1.f;
    float yn  = fmaxf(fminf(nm, maxn), 1e-15f);
    float ratio = (1.f + yn) * frcp(1.f - yn);
    float art = 0.34657359f * flog2_(ratio);
    float k  = inv * ps * alpha * art * frcp(yn);
    float cx = k * Af * s;
    float cy = k * Bf;

    __half2 q0 = __floats2half2_rn(fmaf(cx, h0.x, cy * v0.x), fmaf(cx, h0.y, cy * v0.y));
    __half2 q1 = __floats2half2_rn(fmaf(cx, h1.x, cy * v1.x), fmaf(cx, h1.y, cy * v1.y));
    __half2 q2 = __floats2half2_rn(fmaf(cx, h2.x, cy * v2.x), fmaf(cx, h2.y, cy * v2.y));
    __half2 q3 = __floats2half2_rn(fmaf(cx, h3.x, cy * v3.x), fmaf(cx, h3.y, cy * v3.y));
    if (act) {
        __half2* dst = agg + (size_t)obj * 32 + 4 * j;
        unsafeAtomicAdd(dst + 0, q0);
        unsafeAtomicAdd(dst + 1, q1);
        unsafeAtomicAdd(dst + 2, q2);
        unsafeAtomicAdd(dst + 3, q3);
    }
}

// ================= generic fallback (any A, f32) =================

__global__ void prep_small_kernel(const int* __restrict__ q_rel,
                                  const float* __restrict__ query_embed,
                                  const float* __restrict__ Wqr_w,
                                  const float* __restrict__ Wqr_b,
                                  const float* __restrict__ rela_embed,
                                  const float* __restrict__ Wr,
                                  float* __restrict__ hr_h,
                                  float* __restrict__ hr_aux,
                                  float* __restrict__ preq,
                                  int R, int B, int A) {
    int w = (blockIdx.x * blockDim.x + threadIdx.x) >> 6;
    int lane = threadIdx.x & 63;
    if (w < R) {
        int r = w;
        float u = rela_embed[r * 64 + lane];
        float n2 = wave_sum(u * u);
        float s, y2;
        expmap0_scale(fsqrt_(n2), s, y2);
        hr_h[r * 64 + lane] = s * u;
        for (int a = 0; a < A; ++a) {
            float p = wave_sum(u * Wr[a * 64 + lane]);
            if (lane == 0) hr_aux[r * 8 + a] = p;
        }
        if (lane == 0) hr_aux[r * 8 + 6] = y2;
    } else if (w < R + B) {
        int b = w - R;
        int qr = q_rel[b];
        float q = query_embed[qr * 64 + lane];
        for (int a = 0; a < A; ++a) {
            float p = wave_sum(q * Wqr_w[a * 64 + lane]);
            if (lane == 0) preq[b * 8 + a] = p + Wqr_b[a];
        }
    }
}

__global__ void prep_node_kernel(const float* __restrict__ hidden,
                                 const float* __restrict__ Ws,
                                 float* __restrict__ hs_aux, int N, int A) {
    int w = (blockIdx.x * blockDim.x + threadIdx.x) >> 6;
    if (w >= N) return;
    int lane = threadIdx.x & 63;
    float u = hidden[(size_t)w * 64 + lane];
    float n2 = wave_sum(u * u);
    float s, x2;
    expmap0_scale(fsqrt_(n2), s, x2);
    for (int a = 0; a < A; ++a) {
        float p = wave_sum(u * Ws[a * 64 + lane]);
        if (lane == 0) hs_aux[w * 8 + a] = p;
    }
    if (lane == 0) { hs_aux[w * 8 + 6] = x2; hs_aux[w * 8 + 7] = s; }
}

__global__ void edge_kernel_f32(const int* __restrict__ edges,
                                const float* __restrict__ hidden,
                                const float* __restrict__ hr_h,
                                const float* __restrict__ hr_aux,
                                const float* __restrict__ hs_aux,
                                const float* __restrict__ preq,
                                const float* __restrict__ walpha_w,
                                const float* __restrict__ walpha_b,
                                float* __restrict__ agg,
                                int E, int A) {
    int w = (blockIdx.x * blockDim.x + threadIdx.x) >> 6;
    if (w >= E) return;
    int lane = threadIdx.x & 63;
    const int* er = edges + (size_t)w * 6;
    int r_idx = er[0], rel = er[2], sub = er[4], obj = er[5];

    float s  = hs_aux[(size_t)sub * 8 + 7];
    float x2 = hs_aux[(size_t)sub * 8 + 6];
    float h  = hidden[(size_t)sub * 64 + lane];
    float x  = h * s;
    float y  = hr_h[(size_t)rel * 64 + lane];
    float y2 = hr_aux[(size_t)rel * 8 + 6];
    float xy = wave_sum(x * y);

    float z = walpha_b[0];
    for (int a = 0; a < A; ++a) {
        float pre = hs_aux[(size_t)sub * 8 + a] + hr_aux[(size_t)rel * 8 + a] + preq[(size_t)r_idx * 8 + a];
        z += fmaxf(pre, 0.f) * walpha_w[a];
    }
    float alpha = frcp(1.f + fexp2_(z * -1.44269504f));

    float Af = 1.f + 2.f * xy + y2;
    float Bf = 1.f - x2;
    float den = fmaxf(1.f + 2.f * xy + x2 * y2, 1e-15f);
    float inv = frcp(den);
    float nm2 = fmaxf(Af * Af * x2 + 2.f * Af * Bf * xy + Bf * Bf * y2, 0.f);
    float nm = fsqrt_(nm2) * inv;
    const float maxn = 1.0f - 0.004f;
    float ps = nm > maxn ? maxn * frcp(nm) : 1.f;
    float yn = fmaxf(fminf(nm, maxn), 1e-15f);
    float ratio = (1.f + yn) * frcp(1.f - yn);
    float art = 0.34657359f * flog2_(ratio);
    float k = inv * ps * alpha * art * frcp(yn);
    float msg = fmaf(k * Af * s, h, k * Bf * y);
    unsafeAtomicAdd(agg + (size_t)obj * 64 + lane, msg);
}

// --- final: a = agg @ Wh^T, then p_exp_map + logmap0 ---
template <bool F16>
__global__ void final_kernel_t(float* __restrict__ out,
                               const __half* __restrict__ agg16,
                               const float* __restrict__ Wh,
                               int N) {
    __shared__ float WhT[64 * 64];
    int t = threadIdx.x;
    for (int i = t; i < 64 * 64; i += blockDim.x) {
        int row = i >> 6, col = i & 63;
        WhT[col * 64 + row] = Wh[i];
    }
    __syncthreads();

    int lane = t & 63;
    int wl = t >> 6;
    int wpb = blockDim.x >> 6;
    int wg = blockIdx.x * wpb + wl;
    int wstride = gridDim.x * wpb;

    for (int n = wg; n < N; n += wstride) {
        float v;
        if (F16) v = __half2float(agg16[(size_t)n * 64 + lane]);
        else     v = out[(size_t)n * 64 + lane];
        float a = 0.f;
#pragma unroll
        for (int k = 0; k < 64; ++k)
            a = fmaf(__shfl(v, k, 64), WhT[k * 64 + lane], a);

        float n2 = wave_sum(a * a);
        float na = fsqrt_(n2);
        float nv = fmaxf(na, 1e-10f);
        float pn = tanhf(nv);
        float rinv = frcp(nv);
        float pp = pn * a * rinv;
        float np = pn * (na * rinv);
        float yn = fmaxf(np, 1e-15f);
        float tt = fminf(yn, 1.f - 1e-5f);
        float ratio = (1.f + tt) * frcp(1.f - tt);
        float art = 0.34657359f * flog2_(ratio);
        out[(size_t)n * 64 + lane] = pp * art * frcp(yn);
    }
}

extern "C" void kernel_launch(void* const* d_in, const int* in_sizes, int n_in,
                              void* d_out, int out_size, void* d_ws, size_t ws_size,
                              hipStream_t stream) {
    const int*   q_rel       = (const int*)d_in[1];
    const float* hidden      = (const float*)d_in[2];
    const int*   edges       = (const int*)d_in[3];
    const float* rela_embed  = (const float*)d_in[6];
    const float* query_embed = (const float*)d_in[7];
    const float* Ws          = (const float*)d_in[8];
    const float* Wr          = (const float*)d_in[9];
    const float* Wqr_w       = (const float*)d_in[10];
    const float* Wqr_b       = (const float*)d_in[11];
    const float* walpha_w    = (const float*)d_in[12];
    const float* walpha_b    = (const float*)d_in[13];
    const float* Wh          = (const float*)d_in[14];

    const int D = 64;
    int B = in_sizes[0];
    int E = in_sizes[3] / 6;
    int A = in_sizes[11];
    int R = in_sizes[6] / D;
    int N = out_size / D;

    float* out = (float*)d_out;

    // f16 path workspace layout (all 16B-aligned sizes)
    size_t agg_b    = (size_t)N * 64 * 2;
    size_t hid16_b  = (size_t)N * 64 * 2;
    size_t hsaux_b  = (size_t)N * 16;
    size_t hrh_b    = (size_t)R * 64 * 2;
    size_t hraux_b  = (size_t)R * 16;
    size_t preq_b   = (size_t)B * 16;
    size_t need16   = agg_b + hid16_b + hsaux_b + hrh_b + hraux_b + preq_b;
    bool f16path = (A == 5) && (ws_size >= need16);

    if (f16path) {
        char* base = (char*)d_ws;
        __half2* agg      = (__half2*)base;                 base += agg_b;
        __half*  hidden16 = (__half*)base;                  base += hid16_b;
        uint4*   hs_aux16 = (uint4*)base;                   base += hsaux_b;
        __half*  hr_h16   = (__half*)base;                  base += hrh_b;
        uint4*   hr_aux16 = (uint4*)base;                   base += hraux_b;
        uint4*   preq16   = (uint4*)base;

        hipMemsetAsync(agg, 0, agg_b, stream);

        int waves_small = R + B;
        prep_small16<<<(waves_small * 64 + 255) / 256, 256, 0, stream>>>(
            q_rel, query_embed, Wqr_w, Wqr_b, rela_embed, Wr,
            hr_h16, hr_aux16, preq16, R, B);

        int nwaves = (N + 3) / 4;
        prep_node16<<<(nwaves + 3) / 4, 256, 0, stream>>>(hidden, Ws, hidden16, hs_aux16, N);

        int ewaves = (E + 7) / 8;
        edge_kernel8<<<(ewaves + 3) / 4, 256, 0, stream>>>(
            edges, hidden16, hr_h16, hs_aux16, hr_aux16, preq16,
            walpha_w, walpha_b, agg, E);

        final_kernel_t<true><<<1024, 256, 0, stream>>>(out, (const __half*)agg, Wh, N);
    } else {
        float* hs_aux = (float*)d_ws;
        float* hr_h   = hs_aux + (size_t)N * 8;
        float* hr_aux = hr_h + (size_t)R * 64;
        float* preq   = hr_aux + (size_t)R * 8;

        hipMemsetAsync(d_out, 0, (size_t)out_size * sizeof(float), stream);

        int waves_small = R + B;
        prep_small_kernel<<<(waves_small * 64 + 255) / 256, 256, 0, stream>>>(
            q_rel, query_embed, Wqr_w, Wqr_b, rela_embed, Wr,
            hr_h, hr_aux, preq, R, B, A);

        prep_node_kernel<<<(N + 3) / 4, 256, 0, stream>>>(hidden, Ws, hs_aux, N, A);

        edge_kernel_f32<<<(E + 3) / 4, 256, 0, stream>>>(
            edges, hidden, hr_h, hr_aux, hs_aux, preq,
            walpha_w, walpha_b, out, E, A);

        final_kernel_t<false><<<1024, 256, 0, stream>>>(out, nullptr, Wh, N);
    }
}

// Round 6
// 214.407 us; speedup vs baseline: 2.4293x; 2.4293x over previous
//
#include <hip/hip_runtime.h>
#include <hip/hip_bf16.h>
#include <hip/hip_fp16.h>

// Hyperbolic GNN layer. D = 64.
// Edge kernel: 4 edges/wave (16 lanes/edge), line-aligned f16 pk atomics:
// each atomic instruction covers exactly one 64B cacheline of the agg row.

__device__ __forceinline__ float wave_sum(float v) {
#pragma unroll
    for (int off = 32; off > 0; off >>= 1) v += __shfl_xor(v, off, 64);
    return v;
}

// ---- fast HW math ----
__device__ __forceinline__ float frcp(float x) {
#if __has_builtin(__builtin_amdgcn_rcpf)
    return __builtin_amdgcn_rcpf(x);
#else
    return 1.f / x;
#endif
}
__device__ __forceinline__ float fsqrt_(float x) {
#if __has_builtin(__builtin_amdgcn_sqrtf)
    return __builtin_amdgcn_sqrtf(x);
#else
    return sqrtf(x);
#endif
}
__device__ __forceinline__ float flog2_(float x) {
#if __has_builtin(__builtin_amdgcn_logf)
    return __builtin_amdgcn_logf(x);
#else
    return log2f(x);
#endif
}
__device__ __forceinline__ float fexp2_(float x) {
#if __has_builtin(__builtin_amdgcn_exp2f)
    return __builtin_amdgcn_exp2f(x);
#else
    return exp2f(x);
#endif
}

__device__ __forceinline__ unsigned pk2(float a, float b) {
    __half2 h = __floats2half2_rn(a, b);
    return __builtin_bit_cast(unsigned, h);
}
__device__ __forceinline__ float2 upk2(unsigned u) {
    __half2 h = __builtin_bit_cast(__half2, u);
    return __half22float2(h);
}

// expmap0 scale: s such that expmap0(u) = s*u; x2 = ||s*u||^2
__device__ __forceinline__ void expmap0_scale(float norm, float& s, float& x2) {
    const float maxn = 1.0f - 0.004f;
    float un = fmaxf(norm, 1e-15f);
    float th = tanhf(fminf(un, 15.0f));
    float gs = th / un;
    float ng = gs * norm;
    float ps = ng > maxn ? maxn / ng : 1.0f;
    s = gs * ps;
    float sn = s * norm;
    x2 = sn * sn;
}

// ================= f16 fast path (A == 5) =================

// rel tables (R waves) and query rows (B waves), f16 outputs
__global__ void prep_small16(const int* __restrict__ q_rel,
                             const float* __restrict__ query_embed,
                             const float* __restrict__ Wqr_w,
                             const float* __restrict__ Wqr_b,
                             const float* __restrict__ rela_embed,
                             const float* __restrict__ Wr,
                             __half* __restrict__ hr_h16,   // [R][64]
                             uint4* __restrict__ hr_aux16,  // [R]: {w0..w4,0,y2,0}
                             uint4* __restrict__ preq16,    // [B]: {p0..p4,0,0,0}
                             int R, int B) {
    int w = (blockIdx.x * blockDim.x + threadIdx.x) >> 6;
    int lane = threadIdx.x & 63;
    if (w < R) {
        int r = w;
        float u = rela_embed[r * 64 + lane];
        float p0 = u * u;
        float p1 = u * Wr[0 * 64 + lane];
        float p2 = u * Wr[1 * 64 + lane];
        float p3 = u * Wr[2 * 64 + lane];
        float p4 = u * Wr[3 * 64 + lane];
        float p5 = u * Wr[4 * 64 + lane];
#pragma unroll
        for (int off = 1; off < 64; off <<= 1) {
            p0 += __shfl_xor(p0, off, 64);
            p1 += __shfl_xor(p1, off, 64);
            p2 += __shfl_xor(p2, off, 64);
            p3 += __shfl_xor(p3, off, 64);
            p4 += __shfl_xor(p4, off, 64);
            p5 += __shfl_xor(p5, off, 64);
        }
        float s, y2;
        expmap0_scale(fsqrt_(p0), s, y2);
        hr_h16[r * 64 + lane] = __float2half(s * u);
        if (lane == 0) {
            uint4 o; o.x = pk2(p1, p2); o.y = pk2(p3, p4); o.z = pk2(p5, 0.f); o.w = pk2(y2, 0.f);
            hr_aux16[r] = o;
        }
    } else if (w < R + B) {
        int b = w - R;
        int qr = q_rel[b];
        float q = query_embed[qr * 64 + lane];
        float p1 = q * Wqr_w[0 * 64 + lane];
        float p2 = q * Wqr_w[1 * 64 + lane];
        float p3 = q * Wqr_w[2 * 64 + lane];
        float p4 = q * Wqr_w[3 * 64 + lane];
        float p5 = q * Wqr_w[4 * 64 + lane];
#pragma unroll
        for (int off = 1; off < 64; off <<= 1) {
            p1 += __shfl_xor(p1, off, 64);
            p2 += __shfl_xor(p2, off, 64);
            p3 += __shfl_xor(p3, off, 64);
            p4 += __shfl_xor(p4, off, 64);
            p5 += __shfl_xor(p5, off, 64);
        }
        if (lane == 0) {
            uint4 o;
            o.x = pk2(p1 + Wqr_b[0], p2 + Wqr_b[1]);
            o.y = pk2(p3 + Wqr_b[2], p4 + Wqr_b[3]);
            o.z = pk2(p5 + Wqr_b[4], 0.f);
            o.w = pk2(0.f, 0.f);
            preq16[b] = o;
        }
    }
}

// per-node: hidden16 row + aux {w0..w4,0,x2,s}; quarter-wave, 4 nodes/wave
__global__ void prep_node16(const float* __restrict__ hidden,
                            const float* __restrict__ Ws,
                            __half* __restrict__ hidden16,
                            uint4* __restrict__ hs_aux16,
                            int N) {
    int wid = (blockIdx.x * blockDim.x + threadIdx.x) >> 6;
    int lane = threadIdx.x & 63;
    int q = lane >> 4, j = lane & 15;
    int n = wid * 4 + q;
    bool act = n < N;
    int nc = act ? n : N - 1;

    float4 u = *(const float4*)(hidden + (size_t)nc * 64 + 4 * j);
    float4 w0 = *(const float4*)(Ws + 0 * 64 + 4 * j);
    float4 w1 = *(const float4*)(Ws + 1 * 64 + 4 * j);
    float4 w2 = *(const float4*)(Ws + 2 * 64 + 4 * j);
    float4 w3 = *(const float4*)(Ws + 3 * 64 + 4 * j);
    float4 w4 = *(const float4*)(Ws + 4 * 64 + 4 * j);

#define DOT4(a, b) (fmaf((a).x, (b).x, fmaf((a).y, (b).y, fmaf((a).z, (b).z, (a).w * (b).w))))
    float p0 = DOT4(u, u);
    float p1 = DOT4(u, w0);
    float p2 = DOT4(u, w1);
    float p3 = DOT4(u, w2);
    float p4 = DOT4(u, w3);
    float p5 = DOT4(u, w4);
#undef DOT4
#pragma unroll
    for (int off = 1; off < 16; off <<= 1) {
        p0 += __shfl_xor(p0, off, 64);
        p1 += __shfl_xor(p1, off, 64);
        p2 += __shfl_xor(p2, off, 64);
        p3 += __shfl_xor(p3, off, 64);
        p4 += __shfl_xor(p4, off, 64);
        p5 += __shfl_xor(p5, off, 64);
    }
    float s, x2;
    expmap0_scale(fsqrt_(p0), s, x2);
    if (act) {
        uint2 hp; hp.x = pk2(u.x, u.y); hp.y = pk2(u.z, u.w);
        *(uint2*)(hidden16 + (size_t)n * 64 + 4 * j) = hp;
        if (j == 0) {
            uint4 o; o.x = pk2(p1, p2); o.y = pk2(p3, p4); o.z = pk2(p5, 0.f); o.w = pk2(x2, s);
            hs_aux16[n] = o;
        }
    }
}

// main edge kernel: 4 edges/wave, 16 lanes/edge.
// Lane j owns halfs {2j,2j+1} (line 0) and {32+2j,33+2j} (line 1):
// each of the 2 atomic instructions covers exactly one 64B line.
__global__ __launch_bounds__(256) void edge_kernel4c(
    const int* __restrict__ edges,
    const __half* __restrict__ hidden16,
    const __half* __restrict__ hr_h16,
    const uint4* __restrict__ hs_aux16,
    const uint4* __restrict__ hr_aux16,
    const uint4* __restrict__ preq16,
    const float* __restrict__ walpha_w,
    const float* __restrict__ walpha_b,
    __half2* __restrict__ agg,
    int E)
{
    int wid = (blockIdx.x * blockDim.x + threadIdx.x) >> 6;
    int lane = threadIdx.x & 63;
    int g = lane >> 4;    // which of 4 edges
    int j = lane & 15;    // half2-slot within 64B line

    int e = wid * 4 + g;
    bool act = e < E;
    int ec = act ? e : E - 1;

    const long long* er = (const long long*)(edges + (size_t)ec * 6);
    long long ea  = __builtin_nontemporal_load(er);      // r_idx | dummy
    long long eb  = __builtin_nontemporal_load(er + 1);  // rel | dummy
    long long ecd = __builtin_nontemporal_load(er + 2);  // sub | obj
    int r_idx = (int)(ea & 0xffffffffLL);
    int rel   = (int)(eb & 0xffffffffLL);
    int sub   = (int)(ecd & 0xffffffffLL);
    int obj   = (int)(ecd >> 32);

    uint4 hsa = hs_aux16[sub];
    uint4 hra = hr_aux16[rel];
    uint4 pqa = preq16[r_idx];

    float2 hs01 = upk2(hsa.x), hs23 = upk2(hsa.y), hs4 = upk2(hsa.z), hsxs = upk2(hsa.w);
    float2 hr01 = upk2(hra.x), hr23 = upk2(hra.y), hr4 = upk2(hra.z), hry = upk2(hra.w);
    float2 pq01 = upk2(pqa.x), pq23 = upk2(pqa.y), pq4 = upk2(pqa.z);
    float x2 = hsxs.x, s = hsxs.y, y2 = hry.x;

    // lane j loads half2 at byte 4j (line 0) and 64+4j (line 1)
    const unsigned* hrow = (const unsigned*)(hidden16 + (size_t)sub * 64);
    const unsigned* yrow = (const unsigned*)(hr_h16 + (size_t)rel * 64);
    unsigned hu_lo = hrow[j], hu_hi = hrow[16 + j];
    unsigned yu_lo = yrow[j], yu_hi = yrow[16 + j];
    float2 hl = upk2(hu_lo), hh = upk2(hu_hi);
    float2 yl = upk2(yu_lo), yh = upk2(yu_hi);

    float p = hl.x * yl.x;
    p = fmaf(hl.y, yl.y, p);
    p = fmaf(hh.x, yh.x, p);
    p = fmaf(hh.y, yh.y, p);
    p += __shfl_xor(p, 1, 64);
    p += __shfl_xor(p, 2, 64);
    p += __shfl_xor(p, 4, 64);
    p += __shfl_xor(p, 8, 64);
    float xy = p * s;

    float wa0 = walpha_w[0], wa1 = walpha_w[1], wa2 = walpha_w[2],
          wa3 = walpha_w[3], wa4 = walpha_w[4];
    float z = walpha_b[0];
    z = fmaf(fmaxf(hs01.x + hr01.x + pq01.x, 0.f), wa0, z);
    z = fmaf(fmaxf(hs01.y + hr01.y + pq01.y, 0.f), wa1, z);
    z = fmaf(fmaxf(hs23.x + hr23.x + pq23.x, 0.f), wa2, z);
    z = fmaf(fmaxf(hs23.y + hr23.y + pq23.y, 0.f), wa3, z);
    z = fmaf(fmaxf(hs4.x + hr4.x + pq4.x, 0.f), wa4, z);
    float alpha = frcp(1.f + fexp2_(z * -1.44269504f));

    float Af  = 1.f + 2.f * xy + y2;
    float Bf  = 1.f - x2;
    float den = fmaxf(1.f + 2.f * xy + x2 * y2, 1e-15f);
    float inv = frcp(den);
    float nm2 = fmaxf(fmaf(Af * Af, x2, fmaf(2.f * Af * Bf, xy, Bf * Bf * y2)), 0.f);
    float nm  = fsqrt_(nm2) * inv;
    const float maxn = 1.0f - 0.004f;
    float ps  = nm > maxn ? maxn * frcp(nm) : 1.f;
    float yn  = fmaxf(fminf(nm, maxn), 1e-15f);
    float ratio = (1.f + yn) * frcp(1.f - yn);
    float art = 0.34657359f * flog2_(ratio);
    float k  = inv * ps * alpha * art * frcp(yn);
    float cx = k * Af * s;
    float cy = k * Bf;

    __half2 q_lo = __floats2half2_rn(fmaf(cx, hl.x, cy * yl.x), fmaf(cx, hl.y, cy * yl.y));
    __half2 q_hi = __floats2half2_rn(fmaf(cx, hh.x, cy * yh.x), fmaf(cx, hh.y, cy * yh.y));
    if (act) {
        __half2* dst = agg + (size_t)obj * 32 + j;
        unsafeAtomicAdd(dst, q_lo);        // 16 lanes -> bytes [0,64) of row: 1 line
        unsafeAtomicAdd(dst + 16, q_hi);   // 16 lanes -> bytes [64,128): 1 line
    }
}

// ================= generic fallback (any A, f32) =================

__global__ void prep_small_kernel(const int* __restrict__ q_rel,
                                  const float* __restrict__ query_embed,
                                  const float* __restrict__ Wqr_w,
                                  const float* __restrict__ Wqr_b,
                                  const float* __restrict__ rela_embed,
                                  const float* __restrict__ Wr,
                                  float* __restrict__ hr_h,
                                  float* __restrict__ hr_aux,
                                  float* __restrict__ preq,
                                  int R, int B, int A) {
    int w = (blockIdx.x * blockDim.x + threadIdx.x) >> 6;
    int lane = threadIdx.x & 63;
    if (w < R) {
        int r = w;
        float u = rela_embed[r * 64 + lane];
        float n2 = wave_sum(u * u);
        float s, y2;
        expmap0_scale(fsqrt_(n2), s, y2);
        hr_h[r * 64 + lane] = s * u;
        for (int a = 0; a < A; ++a) {
            float p = wave_sum(u * Wr[a * 64 + lane]);
            if (lane == 0) hr_aux[r * 8 + a] = p;
        }
        if (lane == 0) hr_aux[r * 8 + 6] = y2;
    } else if (w < R + B) {
        int b = w - R;
        int qr = q_rel[b];
        float q = query_embed[qr * 64 + lane];
        for (int a = 0; a < A; ++a) {
            float p = wave_sum(q * Wqr_w[a * 64 + lane]);
            if (lane == 0) preq[b * 8 + a] = p + Wqr_b[a];
        }
    }
}

__global__ void prep_node_kernel(const float* __restrict__ hidden,
                                 const float* __restrict__ Ws,
                                 float* __restrict__ hs_aux, int N, int A) {
    int w = (blockIdx.x * blockDim.x + threadIdx.x) >> 6;
    if (w >= N) return;
    int lane = threadIdx.x & 63;
    float u = hidden[(size_t)w * 64 + lane];
    float n2 = wave_sum(u * u);
    float s, x2;
    expmap0_scale(fsqrt_(n2), s, x2);
    for (int a = 0; a < A; ++a) {
        float p = wave_sum(u * Ws[a * 64 + lane]);
        if (lane == 0) hs_aux[w * 8 + a] = p;
    }
    if (lane == 0) { hs_aux[w * 8 + 6] = x2; hs_aux[w * 8 + 7] = s; }
}

__global__ void edge_kernel_f32(const int* __restrict__ edges,
                                const float* __restrict__ hidden,
                                const float* __restrict__ hr_h,
                                const float* __restrict__ hr_aux,
                                const float* __restrict__ hs_aux,
                                const float* __restrict__ preq,
                                const float* __restrict__ walpha_w,
                                const float* __restrict__ walpha_b,
                                float* __restrict__ agg,
                                int E, int A) {
    int w = (blockIdx.x * blockDim.x + threadIdx.x) >> 6;
    if (w >= E) return;
    int lane = threadIdx.x & 63;
    const int* er = edges + (size_t)w * 6;
    int r_idx = er[0], rel = er[2], sub = er[4], obj = er[5];

    float s  = hs_aux[(size_t)sub * 8 + 7];
    float x2 = hs_aux[(size_t)sub * 8 + 6];
    float h  = hidden[(size_t)sub * 64 + lane];
    float x  = h * s;
    float y  = hr_h[(size_t)rel * 64 + lane];
    float y2 = hr_aux[(size_t)rel * 8 + 6];
    float xy = wave_sum(x * y);

    float z = walpha_b[0];
    for (int a = 0; a < A; ++a) {
        float pre = hs_aux[(size_t)sub * 8 + a] + hr_aux[(size_t)rel * 8 + a] + preq[(size_t)r_idx * 8 + a];
        z += fmaxf(pre, 0.f) * walpha_w[a];
    }
    float alpha = frcp(1.f + fexp2_(z * -1.44269504f));

    float Af = 1.f + 2.f * xy + y2;
    float Bf = 1.f - x2;
    float den = fmaxf(1.f + 2.f * xy + x2 * y2, 1e-15f);
    float inv = frcp(den);
    float nm2 = fmaxf(Af * Af * x2 + 2.f * Af * Bf * xy + Bf * Bf * y2, 0.f);
    float nm = fsqrt_(nm2) * inv;
    const float maxn = 1.0f - 0.004f;
    float ps = nm > maxn ? maxn * frcp(nm) : 1.f;
    float yn = fmaxf(fminf(nm, maxn), 1e-15f);
    float ratio = (1.f + yn) * frcp(1.f - yn);
    float art = 0.34657359f * flog2_(ratio);
    float k = inv * ps * alpha * art * frcp(yn);
    float msg = fmaf(k * Af * s, h, k * Bf * y);
    unsafeAtomicAdd(agg + (size_t)obj * 64 + lane, msg);
}

// --- final: a = agg @ Wh^T, then p_exp_map + logmap0 ---
template <bool F16>
__global__ void final_kernel_t(float* __restrict__ out,
                               const __half* __restrict__ agg16,
                               const float* __restrict__ Wh,
                               int N) {
    __shared__ float WhT[64 * 64];
    int t = threadIdx.x;
    for (int i = t; i < 64 * 64; i += blockDim.x) {
        int row = i >> 6, col = i & 63;
        WhT[col * 64 + row] = Wh[i];
    }
    __syncthreads();

    int lane = t & 63;
    int wl = t >> 6;
    int wpb = blockDim.x >> 6;
    int wg = blockIdx.x * wpb + wl;
    int wstride = gridDim.x * wpb;

    for (int n = wg; n < N; n += wstride) {
        float v;
        if (F16) v = __half2float(agg16[(size_t)n * 64 + lane]);
        else     v = out[(size_t)n * 64 + lane];
        float a = 0.f;
#pragma unroll
        for (int k = 0; k < 64; ++k)
            a = fmaf(__shfl(v, k, 64), WhT[k * 64 + lane], a);

        float n2 = wave_sum(a * a);
        float na = fsqrt_(n2);
        float nv = fmaxf(na, 1e-10f);
        float pn = tanhf(nv);
        float rinv = frcp(nv);
        float pp = pn * a * rinv;
        float np = pn * (na * rinv);
        float yn = fmaxf(np, 1e-15f);
        float tt = fminf(yn, 1.f - 1e-5f);
        float ratio = (1.f + tt) * frcp(1.f - tt);
        float art = 0.34657359f * flog2_(ratio);
        out[(size_t)n * 64 + lane] = pp * art * frcp(yn);
    }
}

extern "C" void kernel_launch(void* const* d_in, const int* in_sizes, int n_in,
                              void* d_out, int out_size, void* d_ws, size_t ws_size,
                              hipStream_t stream) {
    const int*   q_rel       = (const int*)d_in[1];
    const float* hidden      = (const float*)d_in[2];
    const int*   edges       = (const int*)d_in[3];
    const float* rela_embed  = (const float*)d_in[6];
    const float* query_embed = (const float*)d_in[7];
    const float* Ws          = (const float*)d_in[8];
    const float* Wr          = (const float*)d_in[9];
    const float* Wqr_w       = (const float*)d_in[10];
    const float* Wqr_b       = (const float*)d_in[11];
    const float* walpha_w    = (const float*)d_in[12];
    const float* walpha_b    = (const float*)d_in[13];
    const float* Wh          = (const float*)d_in[14];

    const int D = 64;
    int B = in_sizes[0];
    int E = in_sizes[3] / 6;
    int A = in_sizes[11];
    int R = in_sizes[6] / D;
    int N = out_size / D;

    float* out = (float*)d_out;

    // f16 path workspace layout (all 16B-aligned sizes)
    size_t agg_b    = (size_t)N * 64 * 2;
    size_t hid16_b  = (size_t)N * 64 * 2;
    size_t hsaux_b  = (size_t)N * 16;
    size_t hrh_b    = (size_t)R * 64 * 2;
    size_t hraux_b  = (size_t)R * 16;
    size_t preq_b   = (size_t)B * 16;
    size_t need16   = agg_b + hid16_b + hsaux_b + hrh_b + hraux_b + preq_b;
    bool f16path = (A == 5) && (ws_size >= need16);

    if (f16path) {
        char* base = (char*)d_ws;
        __half2* agg      = (__half2*)base;                 base += agg_b;
        __half*  hidden16 = (__half*)base;                  base += hid16_b;
        uint4*   hs_aux16 = (uint4*)base;                   base += hsaux_b;
        __half*  hr_h16   = (__half*)base;                  base += hrh_b;
        uint4*   hr_aux16 = (uint4*)base;                   base += hraux_b;
        uint4*   preq16   = (uint4*)base;

        hipMemsetAsync(agg, 0, agg_b, stream);

        int waves_small = R + B;
        prep_small16<<<(waves_small * 64 + 255) / 256, 256, 0, stream>>>(
            q_rel, query_embed, Wqr_w, Wqr_b, rela_embed, Wr,
            hr_h16, hr_aux16, preq16, R, B);

        int nwaves = (N + 3) / 4;
        prep_node16<<<(nwaves + 3) / 4, 256, 0, stream>>>(hidden, Ws, hidden16, hs_aux16, N);

        int ewaves = (E + 3) / 4;
        edge_kernel4c<<<(ewaves + 3) / 4, 256, 0, stream>>>(
            edges, hidden16, hr_h16, hs_aux16, hr_aux16, preq16,
            walpha_w, walpha_b, agg, E);

        final_kernel_t<true><<<1024, 256, 0, stream>>>(out, (const __half*)agg, Wh, N);
    } else {
        float* hs_aux = (float*)d_ws;
        float* hr_h   = hs_aux + (size_t)N * 8;
        float* hr_aux = hr_h + (size_t)R * 64;
        float* preq   = hr_aux + (size_t)R * 8;

        hipMemsetAsync(d_out, 0, (size_t)out_size * sizeof(float), stream);

        int waves_small = R + B;
        prep_small_kernel<<<(waves_small * 64 + 255) / 256, 256, 0, stream>>>(
            q_rel, query_embed, Wqr_w, Wqr_b, rela_embed, Wr,
            hr_h, hr_aux, preq, R, B, A);

        prep_node_kernel<<<(N + 3) / 4, 256, 0, stream>>>(hidden, Ws, hs_aux, N, A);

        edge_kernel_f32<<<(E + 3) / 4, 256, 0, stream>>>(
            edges, hidden, hr_h, hr_aux, hs_aux, preq,
            walpha_w, walpha_b, out, E, A);

        final_kernel_t<false><<<1024, 256, 0, stream>>>(out, nullptr, Wh, N);
    }
}

// Round 7
// 161.666 us; speedup vs baseline: 3.2218x; 1.3262x over previous
//
#include <hip/hip_runtime.h>
#include <hip/hip_bf16.h>
#include <hip/hip_fp16.h>

// Hyperbolic GNN layer. D = 64.
// R7: fused prep (zero-agg + node + rel/query tables), edge kernel with
// 8 edges/wave (2 quad-groups, line-aligned f16 atomics), register-GEMM final.

__device__ __forceinline__ float wave_sum(float v) {
#pragma unroll
    for (int off = 32; off > 0; off >>= 1) v += __shfl_xor(v, off, 64);
    return v;
}

// ---- fast HW math ----
__device__ __forceinline__ float frcp(float x) {
#if __has_builtin(__builtin_amdgcn_rcpf)
    return __builtin_amdgcn_rcpf(x);
#else
    return 1.f / x;
#endif
}
__device__ __forceinline__ float fsqrt_(float x) {
#if __has_builtin(__builtin_amdgcn_sqrtf)
    return __builtin_amdgcn_sqrtf(x);
#else
    return sqrtf(x);
#endif
}
__device__ __forceinline__ float flog2_(float x) {
#if __has_builtin(__builtin_amdgcn_logf)
    return __builtin_amdgcn_logf(x);
#else
    return log2f(x);
#endif
}
__device__ __forceinline__ float fexp2_(float x) {
#if __has_builtin(__builtin_amdgcn_exp2f)
    return __builtin_amdgcn_exp2f(x);
#else
    return exp2f(x);
#endif
}

__device__ __forceinline__ unsigned pk2(float a, float b) {
    __half2 h = __floats2half2_rn(a, b);
    return __builtin_bit_cast(unsigned, h);
}
__device__ __forceinline__ float2 upk2(unsigned u) {
    __half2 h = __builtin_bit_cast(__half2, u);
    return __half22float2(h);
}

// expmap0 scale: s such that expmap0(u) = s*u; x2 = ||s*u||^2
__device__ __forceinline__ void expmap0_scale(float norm, float& s, float& x2) {
    const float maxn = 1.0f - 0.004f;
    float un = fmaxf(norm, 1e-15f);
    float th = tanhf(fminf(un, 15.0f));
    float gs = th / un;
    float ng = gs * norm;
    float ps = ng > maxn ? maxn / ng : 1.0f;
    s = gs * ps;
    float sn = s * norm;
    x2 = sn * sn;
}

// ================= f16 fast path (A == 5) =================

// Fused prep: node tables + agg zero (first nwaves waves), rel tables (next R),
// query rows (next B).
__global__ void prep_fused16(const int* __restrict__ q_rel,
                             const float* __restrict__ query_embed,
                             const float* __restrict__ Wqr_w,
                             const float* __restrict__ Wqr_b,
                             const float* __restrict__ rela_embed,
                             const float* __restrict__ Wr,
                             const float* __restrict__ hidden,
                             const float* __restrict__ Ws,
                             __half* __restrict__ hidden16,   // [N][64]
                             uint4* __restrict__ hs_aux16,    // [N]
                             __half* __restrict__ hr_h16,     // [R][64]
                             uint4* __restrict__ hr_aux16,    // [R]
                             uint4* __restrict__ preq16,      // [B]
                             __half* __restrict__ agg16,      // [N][64] (zeroed here)
                             int N, int R, int B) {
    int wid = (blockIdx.x * blockDim.x + threadIdx.x) >> 6;
    int lane = threadIdx.x & 63;
    int nwaves = (N + 3) >> 2;
    if (wid < nwaves) {
        int q = lane >> 4, j = lane & 15;
        int n = wid * 4 + q;
        bool act = n < N;
        int nc = act ? n : N - 1;

        float4 u = *(const float4*)(hidden + (size_t)nc * 64 + 4 * j);
        float4 w0 = *(const float4*)(Ws + 0 * 64 + 4 * j);
        float4 w1 = *(const float4*)(Ws + 1 * 64 + 4 * j);
        float4 w2 = *(const float4*)(Ws + 2 * 64 + 4 * j);
        float4 w3 = *(const float4*)(Ws + 3 * 64 + 4 * j);
        float4 w4 = *(const float4*)(Ws + 4 * 64 + 4 * j);

#define DOT4(a, b) (fmaf((a).x, (b).x, fmaf((a).y, (b).y, fmaf((a).z, (b).z, (a).w * (b).w))))
        float p0 = DOT4(u, u);
        float p1 = DOT4(u, w0);
        float p2 = DOT4(u, w1);
        float p3 = DOT4(u, w2);
        float p4 = DOT4(u, w3);
        float p5 = DOT4(u, w4);
#undef DOT4
#pragma unroll
        for (int off = 1; off < 16; off <<= 1) {
            p0 += __shfl_xor(p0, off, 64);
            p1 += __shfl_xor(p1, off, 64);
            p2 += __shfl_xor(p2, off, 64);
            p3 += __shfl_xor(p3, off, 64);
            p4 += __shfl_xor(p4, off, 64);
            p5 += __shfl_xor(p5, off, 64);
        }
        float s, x2;
        expmap0_scale(fsqrt_(p0), s, x2);
        if (act) {
            uint2 hp; hp.x = pk2(u.x, u.y); hp.y = pk2(u.z, u.w);
            *(uint2*)(hidden16 + (size_t)n * 64 + 4 * j) = hp;
            uint2 zz; zz.x = 0u; zz.y = 0u;
            ((uint2*)(agg16 + (size_t)n * 64))[j] = zz;   // zero 128B row
            if (j == 0) {
                uint4 o; o.x = pk2(p1, p2); o.y = pk2(p3, p4); o.z = pk2(p5, 0.f); o.w = pk2(x2, s);
                hs_aux16[n] = o;
            }
        }
        return;
    }
    int w2 = wid - nwaves;
    if (w2 < R) {
        int r = w2;
        float u = rela_embed[r * 64 + lane];
        float p0 = u * u;
        float p1 = u * Wr[0 * 64 + lane];
        float p2 = u * Wr[1 * 64 + lane];
        float p3 = u * Wr[2 * 64 + lane];
        float p4 = u * Wr[3 * 64 + lane];
        float p5 = u * Wr[4 * 64 + lane];
#pragma unroll
        for (int off = 1; off < 64; off <<= 1) {
            p0 += __shfl_xor(p0, off, 64);
            p1 += __shfl_xor(p1, off, 64);
            p2 += __shfl_xor(p2, off, 64);
            p3 += __shfl_xor(p3, off, 64);
            p4 += __shfl_xor(p4, off, 64);
            p5 += __shfl_xor(p5, off, 64);
        }
        float s, y2;
        expmap0_scale(fsqrt_(p0), s, y2);
        hr_h16[r * 64 + lane] = __float2half(s * u);
        if (lane == 0) {
            uint4 o; o.x = pk2(p1, p2); o.y = pk2(p3, p4); o.z = pk2(p5, 0.f); o.w = pk2(y2, 0.f);
            hr_aux16[r] = o;
        }
    } else if (w2 < R + B) {
        int b = w2 - R;
        int qr = q_rel[b];
        float q = query_embed[qr * 64 + lane];
        float p1 = q * Wqr_w[0 * 64 + lane];
        float p2 = q * Wqr_w[1 * 64 + lane];
        float p3 = q * Wqr_w[2 * 64 + lane];
        float p4 = q * Wqr_w[3 * 64 + lane];
        float p5 = q * Wqr_w[4 * 64 + lane];
#pragma unroll
        for (int off = 1; off < 64; off <<= 1) {
            p1 += __shfl_xor(p1, off, 64);
            p2 += __shfl_xor(p2, off, 64);
            p3 += __shfl_xor(p3, off, 64);
            p4 += __shfl_xor(p4, off, 64);
            p5 += __shfl_xor(p5, off, 64);
        }
        if (lane == 0) {
            uint4 o;
            o.x = pk2(p1 + Wqr_b[0], p2 + Wqr_b[1]);
            o.y = pk2(p3 + Wqr_b[2], p4 + Wqr_b[3]);
            o.z = pk2(p5 + Wqr_b[4], 0.f);
            o.w = pk2(0.f, 0.f);
            preq16[b] = o;
        }
    }
}

// per-edge chain for one quad-group (16 lanes/edge); lane j in [0,16)
__device__ __forceinline__ void edge_chain(
    unsigned hu_lo, unsigned hu_hi, unsigned yu_lo, unsigned yu_hi,
    uint4 hsa, uint4 hra, uint4 pqa,
    const float* wa, float wb,
    bool act, __half2* __restrict__ dst /* agg + obj*32 + j */) {
    float2 hs01 = upk2(hsa.x), hs23 = upk2(hsa.y), hs4 = upk2(hsa.z), hsxs = upk2(hsa.w);
    float2 hr01 = upk2(hra.x), hr23 = upk2(hra.y), hr4 = upk2(hra.z), hry = upk2(hra.w);
    float2 pq01 = upk2(pqa.x), pq23 = upk2(pqa.y), pq4 = upk2(pqa.z);
    float x2 = hsxs.x, s = hsxs.y, y2 = hry.x;

    float2 hl = upk2(hu_lo), hh = upk2(hu_hi);
    float2 yl = upk2(yu_lo), yh = upk2(yu_hi);

    float p = hl.x * yl.x;
    p = fmaf(hl.y, yl.y, p);
    p = fmaf(hh.x, yh.x, p);
    p = fmaf(hh.y, yh.y, p);
    p += __shfl_xor(p, 1, 64);
    p += __shfl_xor(p, 2, 64);
    p += __shfl_xor(p, 4, 64);
    p += __shfl_xor(p, 8, 64);
    float xy = p * s;

    float z = wb;
    z = fmaf(fmaxf(hs01.x + hr01.x + pq01.x, 0.f), wa[0], z);
    z = fmaf(fmaxf(hs01.y + hr01.y + pq01.y, 0.f), wa[1], z);
    z = fmaf(fmaxf(hs23.x + hr23.x + pq23.x, 0.f), wa[2], z);
    z = fmaf(fmaxf(hs23.y + hr23.y + pq23.y, 0.f), wa[3], z);
    z = fmaf(fmaxf(hs4.x + hr4.x + pq4.x, 0.f), wa[4], z);
    float alpha = frcp(1.f + fexp2_(z * -1.44269504f));

    float Af  = 1.f + 2.f * xy + y2;
    float Bf  = 1.f - x2;
    float den = fmaxf(1.f + 2.f * xy + x2 * y2, 1e-15f);
    float inv = frcp(den);
    float nm2 = fmaxf(fmaf(Af * Af, x2, fmaf(2.f * Af * Bf, xy, Bf * Bf * y2)), 0.f);
    float nm  = fsqrt_(nm2) * inv;
    const float maxn = 1.0f - 0.004f;
    float ps  = nm > maxn ? maxn * frcp(nm) : 1.f;
    float yn  = fmaxf(fminf(nm, maxn), 1e-15f);
    float ratio = (1.f + yn) * frcp(1.f - yn);
    float art = 0.34657359f * flog2_(ratio);
    float k  = inv * ps * alpha * art * frcp(yn);
    float cx = k * Af * s;
    float cy = k * Bf;

    __half2 q_lo = __floats2half2_rn(fmaf(cx, hl.x, cy * yl.x), fmaf(cx, hl.y, cy * yl.y));
    __half2 q_hi = __floats2half2_rn(fmaf(cx, hh.x, cy * yh.x), fmaf(cx, hh.y, cy * yh.y));
    if (act) {
        unsafeAtomicAdd(dst, q_lo);        // bytes [0,64) of row: 1 line
        unsafeAtomicAdd(dst + 16, q_hi);   // bytes [64,128): 1 line
    }
}

// main edge kernel: 8 edges/wave as two quad-groups; all loads issued upfront.
__global__ __launch_bounds__(256) void edge_kernel8c(
    const int* __restrict__ edges,
    const __half* __restrict__ hidden16,
    const __half* __restrict__ hr_h16,
    const uint4* __restrict__ hs_aux16,
    const uint4* __restrict__ hr_aux16,
    const uint4* __restrict__ preq16,
    const float* __restrict__ walpha_w,
    const float* __restrict__ walpha_b,
    __half2* __restrict__ agg,
    int E)
{
    int wid = (blockIdx.x * blockDim.x + threadIdx.x) >> 6;
    int lane = threadIdx.x & 63;
    int g = lane >> 4;    // quad index
    int j = lane & 15;    // half2-slot within 64B line

    int e0 = wid * 8 + g;
    int e1 = wid * 8 + 4 + g;
    bool act0 = e0 < E, act1 = e1 < E;
    int ec0 = act0 ? e0 : E - 1;
    int ec1 = act1 ? e1 : E - 1;

    const long long* er0 = (const long long*)(edges + (size_t)ec0 * 6);
    const long long* er1 = (const long long*)(edges + (size_t)ec1 * 6);
    long long a0 = __builtin_nontemporal_load(er0);
    long long b0 = __builtin_nontemporal_load(er0 + 1);
    long long c0 = __builtin_nontemporal_load(er0 + 2);
    long long a1 = __builtin_nontemporal_load(er1);
    long long b1 = __builtin_nontemporal_load(er1 + 1);
    long long c1 = __builtin_nontemporal_load(er1 + 2);
    int r0 = (int)a0, rel0 = (int)b0, sub0 = (int)c0, obj0 = (int)(c0 >> 32);
    int r1 = (int)a1, rel1 = (int)b1, sub1 = (int)c1, obj1 = (int)(c1 >> 32);

    uint4 hsa0 = hs_aux16[sub0];
    uint4 hra0 = hr_aux16[rel0];
    uint4 pqa0 = preq16[r0];
    uint4 hsa1 = hs_aux16[sub1];
    uint4 hra1 = hr_aux16[rel1];
    uint4 pqa1 = preq16[r1];

    const unsigned* hrow0 = (const unsigned*)(hidden16 + (size_t)sub0 * 64);
    const unsigned* yrow0 = (const unsigned*)(hr_h16 + (size_t)rel0 * 64);
    const unsigned* hrow1 = (const unsigned*)(hidden16 + (size_t)sub1 * 64);
    const unsigned* yrow1 = (const unsigned*)(hr_h16 + (size_t)rel1 * 64);
    unsigned hu_lo0 = hrow0[j], hu_hi0 = hrow0[16 + j];
    unsigned yu_lo0 = yrow0[j], yu_hi0 = yrow0[16 + j];
    unsigned hu_lo1 = hrow1[j], hu_hi1 = hrow1[16 + j];
    unsigned yu_lo1 = yrow1[j], yu_hi1 = yrow1[16 + j];

    float wa[5];
    wa[0] = walpha_w[0]; wa[1] = walpha_w[1]; wa[2] = walpha_w[2];
    wa[3] = walpha_w[3]; wa[4] = walpha_w[4];
    float wb = walpha_b[0];

    edge_chain(hu_lo0, hu_hi0, yu_lo0, yu_hi0, hsa0, hra0, pqa0, wa, wb,
               act0, agg + (size_t)obj0 * 32 + j);
    edge_chain(hu_lo1, hu_hi1, yu_lo1, yu_hi1, hsa1, hra1, pqa1, wa, wb,
               act1, agg + (size_t)obj1 * 32 + j);
}

// final: register-GEMM. Lane d holds Wh row d (64 f32 regs); agg tile (64 nodes)
// staged in LDS; inner loop = uniform-address ds_read_b64 broadcasts + fmac.
__global__ __launch_bounds__(256) void final_gemm16(
    float* __restrict__ out,
    const __half* __restrict__ agg16,
    const float* __restrict__ Wh,
    int N)
{
    __shared__ __half tile[64 * 64];   // 8 KB
    int t = threadIdx.x;
    int lane = t & 63;
    int w = t >> 6;

    float wh[64];
    const float4* whr = (const float4*)(Wh + (size_t)lane * 64);
#pragma unroll
    for (int i = 0; i < 16; ++i) {
        float4 v = whr[i];
        wh[4 * i] = v.x; wh[4 * i + 1] = v.y; wh[4 * i + 2] = v.z; wh[4 * i + 3] = v.w;
    }

    int ntiles = (N + 63) >> 6;
    for (int ti = blockIdx.x; ti < ntiles; ti += gridDim.x) {
        int base = ti << 6;
        int nrow = min(64, N - base);
        __syncthreads();   // previous tile fully consumed
        {
            const uint2* src = (const uint2*)(agg16 + (size_t)base * 64);
            uint2* dst = (uint2*)tile;
            int nu2 = nrow * 16;
            for (int i = t; i < nu2; i += 256) dst[i] = src[i];
        }
        __syncthreads();
#pragma unroll 1
        for (int r = 0; r < 16; ++r) {
            int n = base + w * 16 + r;
            if (n >= N) break;
            const uint2* arow = (const uint2*)(tile + (w * 16 + r) * 64);
            float acc = 0.f;
#pragma unroll
            for (int kk = 0; kk < 16; ++kk) {
                uint2 u = arow[kk];                 // uniform address -> broadcast
                float2 f0 = upk2(u.x), f1 = upk2(u.y);
                acc = fmaf(f0.x, wh[4 * kk], acc);
                acc = fmaf(f0.y, wh[4 * kk + 1], acc);
                acc = fmaf(f1.x, wh[4 * kk + 2], acc);
                acc = fmaf(f1.y, wh[4 * kk + 3], acc);
            }
            float n2 = wave_sum(acc * acc);
            float na = fsqrt_(n2);
            float nv = fmaxf(na, 1e-10f);
            float pn = tanhf(nv);
            float rinv = frcp(nv);
            float pp = pn * acc * rinv;              // p_exp_map
            float np = pn * (na * rinv);             // ||p||
            float yn = fmaxf(np, 1e-15f);
            float tt = fminf(yn, 1.f - 1e-5f);
            float ratio = (1.f + tt) * frcp(1.f - tt);
            float art = 0.34657359f * flog2_(ratio);
            out[(size_t)n * 64 + lane] = pp * art * frcp(yn);
        }
    }
}

// ================= generic fallback (any A, f32) =================

__global__ void prep_small_kernel(const int* __restrict__ q_rel,
                                  const float* __restrict__ query_embed,
                                  const float* __restrict__ Wqr_w,
                                  const float* __restrict__ Wqr_b,
                                  const float* __restrict__ rela_embed,
                                  const float* __restrict__ Wr,
                                  float* __restrict__ hr_h,
                                  float* __restrict__ hr_aux,
                                  float* __restrict__ preq,
                                  int R, int B, int A) {
    int w = (blockIdx.x * blockDim.x + threadIdx.x) >> 6;
    int lane = threadIdx.x & 63;
    if (w < R) {
        int r = w;
        float u = rela_embed[r * 64 + lane];
        float n2 = wave_sum(u * u);
        float s, y2;
        expmap0_scale(fsqrt_(n2), s, y2);
        hr_h[r * 64 + lane] = s * u;
        for (int a = 0; a < A; ++a) {
            float p = wave_sum(u * Wr[a * 64 + lane]);
            if (lane == 0) hr_aux[r * 8 + a] = p;
        }
        if (lane == 0) hr_aux[r * 8 + 6] = y2;
    } else if (w < R + B) {
        int b = w - R;
        int qr = q_rel[b];
        float q = query_embed[qr * 64 + lane];
        for (int a = 0; a < A; ++a) {
            float p = wave_sum(q * Wqr_w[a * 64 + lane]);
            if (lane == 0) preq[b * 8 + a] = p + Wqr_b[a];
        }
    }
}

__global__ void prep_node_kernel(const float* __restrict__ hidden,
                                 const float* __restrict__ Ws,
                                 float* __restrict__ hs_aux, int N, int A) {
    int w = (blockIdx.x * blockDim.x + threadIdx.x) >> 6;
    if (w >= N) return;
    int lane = threadIdx.x & 63;
    float u = hidden[(size_t)w * 64 + lane];
    float n2 = wave_sum(u * u);
    float s, x2;
    expmap0_scale(fsqrt_(n2), s, x2);
    for (int a = 0; a < A; ++a) {
        float p = wave_sum(u * Ws[a * 64 + lane]);
        if (lane == 0) hs_aux[w * 8 + a] = p;
    }
    if (lane == 0) { hs_aux[w * 8 + 6] = x2; hs_aux[w * 8 + 7] = s; }
}

__global__ void edge_kernel_f32(const int* __restrict__ edges,
                                const float* __restrict__ hidden,
                                const float* __restrict__ hr_h,
                                const float* __restrict__ hr_aux,
                                const float* __restrict__ hs_aux,
                                const float* __restrict__ preq,
                                const float* __restrict__ walpha_w,
                                const float* __restrict__ walpha_b,
                                float* __restrict__ agg,
                                int E, int A) {
    int w = (blockIdx.x * blockDim.x + threadIdx.x) >> 6;
    if (w >= E) return;
    int lane = threadIdx.x & 63;
    const int* er = edges + (size_t)w * 6;
    int r_idx = er[0], rel = er[2], sub = er[4], obj = er[5];

    float s  = hs_aux[(size_t)sub * 8 + 7];
    float x2 = hs_aux[(size_t)sub * 8 + 6];
    float h  = hidden[(size_t)sub * 64 + lane];
    float x  = h * s;
    float y  = hr_h[(size_t)rel * 64 + lane];
    float y2 = hr_aux[(size_t)rel * 8 + 6];
    float xy = wave_sum(x * y);

    float z = walpha_b[0];
    for (int a = 0; a < A; ++a) {
        float pre = hs_aux[(size_t)sub * 8 + a] + hr_aux[(size_t)rel * 8 + a] + preq[(size_t)r_idx * 8 + a];
        z += fmaxf(pre, 0.f) * walpha_w[a];
    }
    float alpha = frcp(1.f + fexp2_(z * -1.44269504f));

    float Af = 1.f + 2.f * xy + y2;
    float Bf = 1.f - x2;
    float den = fmaxf(1.f + 2.f * xy + x2 * y2, 1e-15f);
    float inv = frcp(den);
    float nm2 = fmaxf(Af * Af * x2 + 2.f * Af * Bf * xy + Bf * Bf * y2, 0.f);
    float nm = fsqrt_(nm2) * inv;
    const float maxn = 1.0f - 0.004f;
    float ps = nm > maxn ? maxn * frcp(nm) : 1.f;
    float yn = fmaxf(fminf(nm, maxn), 1e-15f);
    float ratio = (1.f + yn) * frcp(1.f - yn);
    float art = 0.34657359f * flog2_(ratio);
    float k = inv * ps * alpha * art * frcp(yn);
    float msg = fmaf(k * Af * s, h, k * Bf * y);
    unsafeAtomicAdd(agg + (size_t)obj * 64 + lane, msg);
}

__global__ void final_kernel_f32(float* __restrict__ out,
                                 const float* __restrict__ Wh,
                                 int N) {
    __shared__ float WhT[64 * 64];
    int t = threadIdx.x;
    for (int i = t; i < 64 * 64; i += blockDim.x) {
        int row = i >> 6, col = i & 63;
        WhT[col * 64 + row] = Wh[i];
    }
    __syncthreads();

    int lane = t & 63;
    int wl = t >> 6;
    int wpb = blockDim.x >> 6;
    int wg = blockIdx.x * wpb + wl;
    int wstride = gridDim.x * wpb;

    for (int n = wg; n < N; n += wstride) {
        float v = out[(size_t)n * 64 + lane];
        float a = 0.f;
#pragma unroll
        for (int k = 0; k < 64; ++k)
            a = fmaf(__shfl(v, k, 64), WhT[k * 64 + lane], a);

        float n2 = wave_sum(a * a);
        float na = fsqrt_(n2);
        float nv = fmaxf(na, 1e-10f);
        float pn = tanhf(nv);
        float rinv = frcp(nv);
        float pp = pn * a * rinv;
        float np = pn * (na * rinv);
        float yn = fmaxf(np, 1e-15f);
        float tt = fminf(yn, 1.f - 1e-5f);
        float ratio = (1.f + tt) * frcp(1.f - tt);
        float art = 0.34657359f * flog2_(ratio);
        out[(size_t)n * 64 + lane] = pp * art * frcp(yn);
    }
}

extern "C" void kernel_launch(void* const* d_in, const int* in_sizes, int n_in,
                              void* d_out, int out_size, void* d_ws, size_t ws_size,
                              hipStream_t stream) {
    const int*   q_rel       = (const int*)d_in[1];
    const float* hidden      = (const float*)d_in[2];
    const int*   edges       = (const int*)d_in[3];
    const float* rela_embed  = (const float*)d_in[6];
    const float* query_embed = (const float*)d_in[7];
    const float* Ws          = (const float*)d_in[8];
    const float* Wr          = (const float*)d_in[9];
    const float* Wqr_w       = (const float*)d_in[10];
    const float* Wqr_b       = (const float*)d_in[11];
    const float* walpha_w    = (const float*)d_in[12];
    const float* walpha_b    = (const float*)d_in[13];
    const float* Wh          = (const float*)d_in[14];

    const int D = 64;
    int B = in_sizes[0];
    int E = in_sizes[3] / 6;
    int A = in_sizes[11];
    int R = in_sizes[6] / D;
    int N = out_size / D;

    float* out = (float*)d_out;

    size_t agg_b    = (size_t)N * 64 * 2;
    size_t hid16_b  = (size_t)N * 64 * 2;
    size_t hsaux_b  = (size_t)N * 16;
    size_t hrh_b    = (size_t)R * 64 * 2;
    size_t hraux_b  = (size_t)R * 16;
    size_t preq_b   = (size_t)B * 16;
    size_t need16   = agg_b + hid16_b + hsaux_b + hrh_b + hraux_b + preq_b;
    bool f16path = (A == 5) && (ws_size >= need16);

    if (f16path) {
        char* base = (char*)d_ws;
        __half2* agg      = (__half2*)base;                 base += agg_b;
        __half*  hidden16 = (__half*)base;                  base += hid16_b;
        uint4*   hs_aux16 = (uint4*)base;                   base += hsaux_b;
        __half*  hr_h16   = (__half*)base;                  base += hrh_b;
        uint4*   hr_aux16 = (uint4*)base;                   base += hraux_b;
        uint4*   preq16   = (uint4*)base;

        int nwaves = (N + 3) / 4;
        int total_waves = nwaves + R + B;
        prep_fused16<<<(total_waves + 3) / 4, 256, 0, stream>>>(
            q_rel, query_embed, Wqr_w, Wqr_b, rela_embed, Wr,
            hidden, Ws, hidden16, hs_aux16, hr_h16, hr_aux16, preq16,
            (__half*)agg, N, R, B);

        int ewaves = (E + 7) / 8;
        edge_kernel8c<<<(ewaves + 3) / 4, 256, 0, stream>>>(
            edges, hidden16, hr_h16, hs_aux16, hr_aux16, preq16,
            walpha_w, walpha_b, agg, E);

        final_gemm16<<<1024, 256, 0, stream>>>(out, (const __half*)agg, Wh, N);
    } else {
        float* hs_aux = (float*)d_ws;
        float* hr_h   = hs_aux + (size_t)N * 8;
        float* hr_aux = hr_h + (size_t)R * 64;
        float* preq   = hr_aux + (size_t)R * 8;

        hipMemsetAsync(d_out, 0, (size_t)out_size * sizeof(float), stream);

        int waves_small = R + B;
        prep_small_kernel<<<(waves_small * 64 + 255) / 256, 256, 0, stream>>>(
            q_rel, query_embed, Wqr_w, Wqr_b, rela_embed, Wr,
            hr_h, hr_aux, preq, R, B, A);

        prep_node_kernel<<<(N + 3) / 4, 256, 0, stream>>>(hidden, Ws, hs_aux, N, A);

        edge_kernel_f32<<<(E + 3) / 4, 256, 0, stream>>>(
            edges, hidden, hr_h, hr_aux, hs_aux, preq,
            walpha_w, walpha_b, out, E, A);

        final_kernel_f32<<<1024, 256, 0, stream>>>(out, Wh, N);
    }
}